// Round 3
// baseline (1053.962 us; speedup 1.0000x reference)
//
#include <hip/hip_runtime.h>

#define N_NODES 100000
#define IN_DIM 256
#define OUT_DIM 64
#define GEMM_ROWS 32
#define TILE_NODES 128                 // dst-tile size (pow2: cheap >>7 / &127)
#define NTILES ((N_NODES + TILE_NODES - 1) / TILE_NODES)   // 782
#define TCAP 2560                      // per-tile edge capacity: mu=2048, +11 sigma

// ---------------- fused: deg_out histogram + bucket edges by dst-tile ----------------
// cnt_tile is padded to one counter per 32B sector (stride 8 ints) so the 782
// hot-counter atomic chains proceed in parallel at the memory-side atomic units.
__global__ __launch_bounds__(256) void count_scatter_kernel(const int* __restrict__ src,
                                                            const int* __restrict__ dst,
                                                            int* __restrict__ deg_out,
                                                            int* __restrict__ cnt_tile,
                                                            int* __restrict__ buf, int E) {
    int i = blockIdx.x * blockDim.x + threadIdx.x;
    int stride = gridDim.x * blockDim.x;
    int n4 = E >> 2;
    const int4* s4 = (const int4*)src;
    const int4* d4 = (const int4*)dst;
    for (int k = i; k < n4; k += stride) {
        int4 a = s4[k];
        int4 c = d4[k];
        atomicAdd(&deg_out[a.x], 1);
        { int t = c.x >> 7; int sl = atomicAdd(&cnt_tile[t * 8], 1);
          if (sl < TCAP) buf[t * TCAP + sl] = (a.x << 7) | (c.x & 127); }
        atomicAdd(&deg_out[a.y], 1);
        { int t = c.y >> 7; int sl = atomicAdd(&cnt_tile[t * 8], 1);
          if (sl < TCAP) buf[t * TCAP + sl] = (a.y << 7) | (c.y & 127); }
        atomicAdd(&deg_out[a.z], 1);
        { int t = c.z >> 7; int sl = atomicAdd(&cnt_tile[t * 8], 1);
          if (sl < TCAP) buf[t * TCAP + sl] = (a.z << 7) | (c.z & 127); }
        atomicAdd(&deg_out[a.w], 1);
        { int t = c.w >> 7; int sl = atomicAdd(&cnt_tile[t * 8], 1);
          if (sl < TCAP) buf[t * TCAP + sl] = (a.w << 7) | (c.w & 127); }
    }
    int t0 = n4 * 4 + i;
    if (t0 < E) {
        int s = src[t0], d = dst[t0];
        atomicAdd(&deg_out[s], 1);
        int t = d >> 7; int sl = atomicAdd(&cnt_tile[t * 8], 1);
        if (sl < TCAP) buf[t * TCAP + sl] = (s << 7) | (d & 127);
    }
}

// ---------------- x = (h * rsqrt(deg_out)[:,None]) @ W ----------------
// 32 rows/block in LDS; thread (rg=t>>5, j=t&31) computes 4 rows x 2 cols (j, j+32):
// 8 FMAs per ds_read_b128 -> VALU-bound, not LDS-bound.
__global__ __launch_bounds__(256) void gemm_kernel(const float* __restrict__ h,
                                                   const float* __restrict__ W,
                                                   const int* __restrict__ deg_out,
                                                   float* __restrict__ x) {
    __shared__ float hs[GEMM_ROWS * IN_DIM];
    const int row0 = blockIdx.x * GEMM_ROWS;
    const int t = threadIdx.x;

    const float4* hsrc = (const float4*)(h + (size_t)row0 * IN_DIM);
    float4* hdst = (float4*)hs;
#pragma unroll
    for (int it = 0; it < (GEMM_ROWS * IN_DIM / 4) / 256; ++it) {
        int f = t + it * 256;
        int row = f >> 6;               // f*4 / 256
        int d = deg_out[row0 + row];
        float nrm = rsqrtf((float)(d < 1 ? 1 : d));
        float4 v = hsrc[f];
        v.x *= nrm; v.y *= nrm; v.z *= nrm; v.w *= nrm;
        hdst[f] = v;
    }
    __syncthreads();

    const int j = t & 31;
    const int rg = t >> 5;              // 8 groups x 4 rows
    float acc0[4] = {0.f, 0.f, 0.f, 0.f};
    float acc1[4] = {0.f, 0.f, 0.f, 0.f};

    for (int k = 0; k < IN_DIM; k += 4) {
        float wa0 = W[(k + 0) * OUT_DIM + j],      wb0 = W[(k + 0) * OUT_DIM + j + 32];
        float wa1 = W[(k + 1) * OUT_DIM + j],      wb1 = W[(k + 1) * OUT_DIM + j + 32];
        float wa2 = W[(k + 2) * OUT_DIM + j],      wb2 = W[(k + 2) * OUT_DIM + j + 32];
        float wa3 = W[(k + 3) * OUT_DIM + j],      wb3 = W[(k + 3) * OUT_DIM + j + 32];
#pragma unroll
        for (int r = 0; r < 4; ++r) {
            const float4 hv = *(const float4*)&hs[(rg * 4 + r) * IN_DIM + k];
            acc0[r] = fmaf(hv.x, wa0, acc0[r]);
            acc0[r] = fmaf(hv.y, wa1, acc0[r]);
            acc0[r] = fmaf(hv.z, wa2, acc0[r]);
            acc0[r] = fmaf(hv.w, wa3, acc0[r]);
            acc1[r] = fmaf(hv.x, wb0, acc1[r]);
            acc1[r] = fmaf(hv.y, wb1, acc1[r]);
            acc1[r] = fmaf(hv.z, wb2, acc1[r]);
            acc1[r] = fmaf(hv.w, wb3, acc1[r]);
        }
    }

#pragma unroll
    for (int r = 0; r < 4; ++r) {
        int row = row0 + rg * 4 + r;
        x[(size_t)row * OUT_DIM + j]      = acc0[r];
        x[(size_t)row * OUT_DIM + j + 32] = acc1[r];
    }
}

// ---------------- per-tile aggregate: LDS accumulation, no global atomics ----------------
__global__ __launch_bounds__(256) void aggregate_kernel(const int* __restrict__ cnt_tile,
                                                        const int* __restrict__ buf,
                                                        const float* __restrict__ x,
                                                        const float* __restrict__ b,
                                                        float* __restrict__ out) {
    __shared__ float acc[TILE_NODES * OUT_DIM];   // 32 KB
    __shared__ int cntl[TILE_NODES];
    const int tile = blockIdx.x;
    const int t = threadIdx.x;
    const int lane = t & 63;
    const int wid = t >> 6;

    // zero LDS
    float4* az = (float4*)acc;
#pragma unroll
    for (int i = 0; i < (TILE_NODES * OUT_DIM / 4) / 256; ++i)
        az[t + i * 256] = make_float4(0.f, 0.f, 0.f, 0.f);
    if (t < TILE_NODES) cntl[t] = 0;
    __syncthreads();

    int cnt = cnt_tile[tile * 8];
    if (cnt > TCAP) cnt = TCAP;
    const int* tb = buf + tile * TCAP;

    // per-node in-degree (for norm_dst)
    for (int k = t; k < cnt; k += 256) atomicAdd(&cntl[tb[k] & 127], 1);

    // accumulate: each wave takes 64-entry batches; 8 gathers in flight
    for (int base = wid * 64; base < cnt; base += 256) {
        int k = base + lane;
        int packed = (k < cnt) ? tb[k] : 0;
        int m = cnt - base; if (m > 64) m = 64;
        int i = 0;
        for (; i + 8 <= m; i += 8) {
            int p[8]; float v[8];
#pragma unroll
            for (int u = 0; u < 8; ++u) p[u] = __shfl(packed, i + u);
#pragma unroll
            for (int u = 0; u < 8; ++u) v[u] = x[(size_t)(p[u] >> 7) * OUT_DIM + lane];
#pragma unroll
            for (int u = 0; u < 8; ++u) atomicAdd(&acc[(p[u] & 127) * OUT_DIM + lane], v[u]);
        }
        for (; i < m; ++i) {
            int p = __shfl(packed, i);
            float v = x[(size_t)(p >> 7) * OUT_DIM + lane];
            atomicAdd(&acc[(p & 127) * OUT_DIM + lane], v);
        }
    }
    __syncthreads();

    // epilogue: out = relu(acc * rsqrt(max(deg_in,1)) + b)
    float bc = b[lane];
    for (int n = wid; n < TILE_NODES; n += 4) {
        int node = tile * TILE_NODES + n;
        if (node >= N_NODES) break;
        int c = cntl[n];
        float nrm = rsqrtf((float)(c < 1 ? 1 : c));
        float r = fmaf(acc[n * OUT_DIM + lane], nrm, bc);
        out[(size_t)node * OUT_DIM + lane] = r > 0.f ? r : 0.f;
    }
}

extern "C" void kernel_launch(void* const* d_in, const int* in_sizes, int n_in,
                              void* d_out, int out_size, void* d_ws, size_t ws_size,
                              hipStream_t stream) {
    const float* h   = (const float*)d_in[0];
    const int*   src = (const int*)d_in[1];
    const int*   dst = (const int*)d_in[2];
    const float* W   = (const float*)d_in[3];
    const float* b   = (const float*)d_in[4];
    float* out = (float*)d_out;
    const int E = in_sizes[1];

    // workspace layout (16B aligned): total ~34.0 MB
    char* ws = (char*)d_ws;
    int* deg_out  = (int*)(ws);                     // N ints            (400,000 B)
    int* cnt_tile = (int*)(ws + 400000);            // NTILES*8 ints     ( 25,024 B)
    int* buf      = (int*)(ws + 425024);            // NTILES*TCAP ints  (8,007,680 B)
    float* x      = (float*)(ws + 8432704);         // N*64 floats       (25,600,000 B)

    hipMemsetAsync(deg_out, 0, 425024, stream);     // deg_out + cnt_tile

    count_scatter_kernel<<<1024, 256, 0, stream>>>(src, dst, deg_out, cnt_tile, buf, E);
    gemm_kernel<<<N_NODES / GEMM_ROWS, 256, 0, stream>>>(h, W, deg_out, x);
    aggregate_kernel<<<NTILES, 256, 0, stream>>>(cnt_tile, buf, x, b, out);
}

// Round 4
// 522.713 us; speedup vs baseline: 2.0163x; 2.0163x over previous
//
#include <hip/hip_runtime.h>
#include <hip/hip_fp16.h>

#define N_NODES 100000
#define IN_DIM 256
#define OUT_DIM 64
#define GEMM_ROWS 32
#define SCAN_CHUNK 2048   // 256 threads * 8 elements
#define NSCAN_BLOCKS ((N_NODES + SCAN_CHUNK - 1) / SCAN_CHUNK)  // 49

// ---------------- deg_in histogram (only histogram needed before the scan) ----------------
__global__ __launch_bounds__(256) void deg_in_kernel(const int* __restrict__ dst,
                                                     int* __restrict__ deg_in, int E) {
    int i = blockIdx.x * blockDim.x + threadIdx.x;
    int stride = gridDim.x * blockDim.x;
    int n4 = E >> 2;
    const int4* d4 = (const int4*)dst;
    for (int k = i; k < n4; k += stride) {
        int4 c = d4[k];
        atomicAdd(&deg_in[c.x], 1); atomicAdd(&deg_in[c.y], 1);
        atomicAdd(&deg_in[c.z], 1); atomicAdd(&deg_in[c.w], 1);
    }
    int t = n4 * 4 + i;
    if (t < E) atomicAdd(&deg_in[dst[t]], 1);
}

// ---------------- per-block exclusive scan of deg_in ----------------
__global__ __launch_bounds__(256) void scan_blocks_kernel(const int* __restrict__ deg_in,
                                                          int* __restrict__ offs,
                                                          int* __restrict__ blocksums) {
    const int t = threadIdx.x;
    const int base = blockIdx.x * SCAN_CHUNK + t * 8;
    int pre[8];
    int s = 0;
#pragma unroll
    for (int r = 0; r < 8; ++r) {
        int v = (base + r < N_NODES) ? deg_in[base + r] : 0;
        pre[r] = s; s += v;
    }
    const int lane = t & 63;
    int incl = s;
#pragma unroll
    for (int off = 1; off < 64; off <<= 1) {
        int y = __shfl_up(incl, off);
        if (lane >= off) incl += y;
    }
    int wave_excl = incl - s;
    __shared__ int wtot[4];
    if (lane == 63) wtot[t >> 6] = incl;
    __syncthreads();
    int woff = 0;
    for (int w = 0; w < (t >> 6); ++w) woff += wtot[w];
    int bexcl = woff + wave_excl;
#pragma unroll
    for (int r = 0; r < 8; ++r)
        if (base + r < N_NODES) offs[base + r] = bexcl + pre[r];
    if (t == 0) blocksums[blockIdx.x] = wtot[0] + wtot[1] + wtot[2] + wtot[3];
}

// ---------------- scan the 49 block sums (single wave) ----------------
__global__ void scan_sums_kernel(int* __restrict__ blocksums) {
    int lane = threadIdx.x;
    int v = (lane < NSCAN_BLOCKS) ? blocksums[lane] : 0;
    int incl = v;
#pragma unroll
    for (int off = 1; off < 64; off <<= 1) {
        int y = __shfl_up(incl, off);
        if (lane >= off) incl += y;
    }
    if (lane < NSCAN_BLOCKS) blocksums[lane] = incl - v;
}

// ---------------- add block offsets; init cursors ----------------
__global__ __launch_bounds__(256) void add_offsets_kernel(int* __restrict__ offs,
                                                          int* __restrict__ cur,
                                                          const int* __restrict__ blocksums) {
    int i = blockIdx.x * blockDim.x + threadIdx.x;
    if (i >= N_NODES) return;
    int o = offs[i] + blocksums[i / SCAN_CHUNK];
    offs[i] = o;
    cur[i] = o;
}

// ---------------- CSR fill + fused deg_out histogram ----------------
__global__ __launch_bounds__(256) void fill_deg_kernel(const int* __restrict__ src,
                                                       const int* __restrict__ dst,
                                                       int* __restrict__ cur,
                                                       int* __restrict__ csr_src,
                                                       int* __restrict__ deg_out, int E) {
    int i = blockIdx.x * blockDim.x + threadIdx.x;
    int stride = gridDim.x * blockDim.x;
    int n4 = E >> 2;
    const int4* src4 = (const int4*)src;
    const int4* dst4 = (const int4*)dst;
    for (int k = i; k < n4; k += stride) {
        int4 a = src4[k];
        int4 c = dst4[k];
        atomicAdd(&deg_out[a.x], 1);
        atomicAdd(&deg_out[a.y], 1);
        atomicAdd(&deg_out[a.z], 1);
        atomicAdd(&deg_out[a.w], 1);
        csr_src[atomicAdd(&cur[c.x], 1)] = a.x;
        csr_src[atomicAdd(&cur[c.y], 1)] = a.y;
        csr_src[atomicAdd(&cur[c.z], 1)] = a.z;
        csr_src[atomicAdd(&cur[c.w], 1)] = a.w;
    }
    int t = n4 * 4 + i;
    if (t < E) {
        int s = src[t];
        atomicAdd(&deg_out[s], 1);
        csr_src[atomicAdd(&cur[dst[t]], 1)] = s;
    }
}

// ---------------- x = (h * rsqrt(deg_out)[:,None]) @ W   (fp16 output) ----------------
// thread (rg=t>>5, j=t&31): 4 rows x cols (2j, 2j+1); W loaded as coalesced float2;
// epilogue packs half2 -> coalesced 4B stores.
__global__ __launch_bounds__(256) void gemm_kernel(const float* __restrict__ h,
                                                   const float* __restrict__ W,
                                                   const int* __restrict__ deg_out,
                                                   __half* __restrict__ xh) {
    __shared__ float hs[GEMM_ROWS * IN_DIM];
    const int row0 = blockIdx.x * GEMM_ROWS;
    const int t = threadIdx.x;

    const float4* hsrc = (const float4*)(h + (size_t)row0 * IN_DIM);
    float4* hdst = (float4*)hs;
#pragma unroll
    for (int it = 0; it < (GEMM_ROWS * IN_DIM / 4) / 256; ++it) {
        int f = t + it * 256;
        int row = f >> 6;               // f*4 / 256
        int d = deg_out[row0 + row];
        float nrm = rsqrtf((float)(d < 1 ? 1 : d));
        float4 v = hsrc[f];
        v.x *= nrm; v.y *= nrm; v.z *= nrm; v.w *= nrm;
        hdst[f] = v;
    }
    __syncthreads();

    const int j = t & 31;               // column pair (2j, 2j+1)
    const int rg = t >> 5;              // 8 groups x 4 rows
    const float2* W2 = (const float2*)W;
    float acc0[4] = {0.f, 0.f, 0.f, 0.f};
    float acc1[4] = {0.f, 0.f, 0.f, 0.f};

    for (int k = 0; k < IN_DIM; k += 4) {
        float2 w0 = W2[(k + 0) * 32 + j];
        float2 w1 = W2[(k + 1) * 32 + j];
        float2 w2 = W2[(k + 2) * 32 + j];
        float2 w3 = W2[(k + 3) * 32 + j];
#pragma unroll
        for (int r = 0; r < 4; ++r) {
            const float4 hv = *(const float4*)&hs[(rg * 4 + r) * IN_DIM + k];
            acc0[r] = fmaf(hv.x, w0.x, acc0[r]);  acc1[r] = fmaf(hv.x, w0.y, acc1[r]);
            acc0[r] = fmaf(hv.y, w1.x, acc0[r]);  acc1[r] = fmaf(hv.y, w1.y, acc1[r]);
            acc0[r] = fmaf(hv.z, w2.x, acc0[r]);  acc1[r] = fmaf(hv.z, w2.y, acc1[r]);
            acc0[r] = fmaf(hv.w, w3.x, acc0[r]);  acc1[r] = fmaf(hv.w, w3.y, acc1[r]);
        }
    }

    __half2* x2 = (__half2*)xh;
#pragma unroll
    for (int r = 0; r < 4; ++r) {
        int row = row0 + rg * 4 + r;
        x2[(size_t)row * 32 + j] = __float22half2_rn(make_float2(acc0[r], acc1[r]));
    }
}

// ---------------- aggregate: one wave per node, 4 edges per instruction ----------------
// lane = 16*g + c: group g handles edge (rb+4q+g), lane-part c loads 8B (4 halfs,
// cols 4c..4c+3). 16 edges in flight per staged group. Reduce over g via shfl_xor.
__global__ __launch_bounds__(256) void aggregate_kernel(const int* __restrict__ offs,
                                                        const int* __restrict__ cur,
                                                        const int* __restrict__ csr_src,
                                                        const __half* __restrict__ xh,
                                                        const float* __restrict__ b,
                                                        float* __restrict__ out) {
    const int t = threadIdx.x;
    const int lane = t & 63;
    const int wid = t >> 6;
    const int node = blockIdx.x * 4 + wid;          // 25000*4 == N_NODES exactly
    const int g = lane >> 4;
    const int c = lane & 15;

    const int start = offs[node];
    const int cnt = cur[node] - start;

    float4 acc = make_float4(0.f, 0.f, 0.f, 0.f);
    for (int base = 0; base < cnt; base += 64) {
        int k = base + lane;
        int sidx = (k < cnt) ? csr_src[start + k] : 0;
        int m = cnt - base; if (m > 64) m = 64;
        for (int rb = 0; rb < m; rb += 16) {
            uint2 raw[4]; float wq[4];
#pragma unroll
            for (int q = 0; q < 4; ++q) {
                int e = rb + 4 * q + g;              // <= 63 always
                int s = __shfl(sidx, e);
                bool val = e < m;
                s = val ? s : 0;
                wq[q] = val ? 1.f : 0.f;
                raw[q] = *(const uint2*)(xh + (size_t)s * OUT_DIM + 4 * c);
            }
#pragma unroll
            for (int q = 0; q < 4; ++q) {
                float2 f01 = __half22float2(*(__half2*)&raw[q].x);
                float2 f23 = __half22float2(*(__half2*)&raw[q].y);
                acc.x = fmaf(wq[q], f01.x, acc.x);
                acc.y = fmaf(wq[q], f01.y, acc.y);
                acc.z = fmaf(wq[q], f23.x, acc.z);
                acc.w = fmaf(wq[q], f23.y, acc.w);
            }
        }
    }

    acc.x += __shfl_xor(acc.x, 16);  acc.x += __shfl_xor(acc.x, 32);
    acc.y += __shfl_xor(acc.y, 16);  acc.y += __shfl_xor(acc.y, 32);
    acc.z += __shfl_xor(acc.z, 16);  acc.z += __shfl_xor(acc.z, 32);
    acc.w += __shfl_xor(acc.w, 16);  acc.w += __shfl_xor(acc.w, 32);

    if (g == 0) {
        float nrm = rsqrtf((float)(cnt < 1 ? 1 : cnt));
        float4 bv = ((const float4*)b)[c];
        float4 r;
        r.x = fmaf(acc.x, nrm, bv.x); r.x = r.x > 0.f ? r.x : 0.f;
        r.y = fmaf(acc.y, nrm, bv.y); r.y = r.y > 0.f ? r.y : 0.f;
        r.z = fmaf(acc.z, nrm, bv.z); r.z = r.z > 0.f ? r.z : 0.f;
        r.w = fmaf(acc.w, nrm, bv.w); r.w = r.w > 0.f ? r.w : 0.f;
        ((float4*)out)[(size_t)node * 16 + c] = r;
    }
}

extern "C" void kernel_launch(void* const* d_in, const int* in_sizes, int n_in,
                              void* d_out, int out_size, void* d_ws, size_t ws_size,
                              hipStream_t stream) {
    const float* h   = (const float*)d_in[0];
    const int*   src = (const int*)d_in[1];
    const int*   dst = (const int*)d_in[2];
    const float* W   = (const float*)d_in[3];
    const float* b   = (const float*)d_in[4];
    float* out = (float*)d_out;
    const int E = in_sizes[1];

    // workspace layout (16B aligned), total ~20.8 MB
    char* ws = (char*)d_ws;
    int*    deg_in    = (int*)(ws);                  // N ints
    int*    deg_out   = (int*)(ws + 400000);         // N ints
    int*    offs      = (int*)(ws + 800000);         // N ints
    int*    cur       = (int*)(ws + 1200000);        // N ints
    int*    blocksums = (int*)(ws + 1600000);        // 64 ints
    int*    csr_src   = (int*)(ws + 1600256);        // E ints (6.4 MB)
    __half* xh        = (__half*)(ws + 8000256);     // N*64 halfs (12.8 MB)

    hipMemsetAsync(deg_in, 0, 800000, stream);       // deg_in + deg_out

    deg_in_kernel<<<2048, 256, 0, stream>>>(dst, deg_in, E);
    scan_blocks_kernel<<<NSCAN_BLOCKS, 256, 0, stream>>>(deg_in, offs, blocksums);
    scan_sums_kernel<<<1, 64, 0, stream>>>(blocksums);
    add_offsets_kernel<<<(N_NODES + 255) / 256, 256, 0, stream>>>(offs, cur, blocksums);
    fill_deg_kernel<<<2048, 256, 0, stream>>>(src, dst, cur, csr_src, deg_out, E);
    gemm_kernel<<<N_NODES / GEMM_ROWS, 256, 0, stream>>>(h, W, deg_out, xh);
    aggregate_kernel<<<N_NODES / 4, 256, 0, stream>>>(offs, cur, csr_src, xh, b, out);
}

// Round 5
// 377.399 us; speedup vs baseline: 2.7927x; 1.3850x over previous
//
#include <hip/hip_runtime.h>
#include <hip/hip_fp16.h>

#define N_NODES 100000
#define IN_DIM 256
#define OUT_DIM 64
#define GEMM_ROWS 32
#define NT 782                 // dst/src tiles of 128 nodes
#define NB 256                 // binning blocks
#define SCHUNK 4096            // scan chunk: 256 threads * 16
#define SB ((NT * NB + SCHUNK - 1) / SCHUNK)   // 49 scan blocks per array
#define SCAN_M (NT * NB)       // 200192

// ---------------- pass 1: per-block LDS histograms of dst>>7 and src>>7 ----------------
__global__ __launch_bounds__(256) void count_kernel(const int* __restrict__ src,
                                                    const int* __restrict__ dst,
                                                    int* __restrict__ CD, int* __restrict__ CS,
                                                    int E, int chunk) {
    __shared__ int hd[NT], hs[NT];
    const int t = threadIdx.x, blk = blockIdx.x;
    for (int i = t; i < NT; i += 256) { hd[i] = 0; hs[i] = 0; }
    __syncthreads();
    const int lo = blk * chunk;
    int hi = lo + chunk; if (hi > E) hi = E;
    for (int i = lo + t; i < hi; i += 256) {
        atomicAdd(&hd[dst[i] >> 7], 1);
        atomicAdd(&hs[src[i] >> 7], 1);
    }
    __syncthreads();
    for (int i = t; i < NT; i += 256) {
        CD[i * NB + blk] = hd[i];
        CS[i * NB + blk] = hs[i];
    }
}

// ---------------- pass 2a: chunk-local exclusive scan of CD and CS (in place) ----------------
__global__ __launch_bounds__(256) void scan_blocks_kernel(int* __restrict__ CD, int* __restrict__ CS,
                                                          int* __restrict__ BSD, int* __restrict__ BSS) {
    int cid = blockIdx.x;
    int* arr; int* bs;
    if (cid < SB) { arr = CD; bs = BSD; } else { arr = CS; bs = BSS; cid -= SB; }
    const int t = threadIdx.x;
    const int base = cid * SCHUNK + t * 16;
    int pre[16];
    int s = 0;
#pragma unroll
    for (int r = 0; r < 16; ++r) {
        int v = (base + r < SCAN_M) ? arr[base + r] : 0;
        pre[r] = s; s += v;
    }
    const int lane = t & 63;
    int incl = s;
#pragma unroll
    for (int off = 1; off < 64; off <<= 1) {
        int y = __shfl_up(incl, off);
        if (lane >= off) incl += y;
    }
    int wave_excl = incl - s;
    __shared__ int wtot[4];
    if (lane == 63) wtot[t >> 6] = incl;
    __syncthreads();
    int woff = 0;
    for (int w = 0; w < (t >> 6); ++w) woff += wtot[w];
    int bexcl = woff + wave_excl;
#pragma unroll
    for (int r = 0; r < 16; ++r)
        if (base + r < SCAN_M) arr[base + r] = bexcl + pre[r];
    if (t == 0) bs[cid] = wtot[0] + wtot[1] + wtot[2] + wtot[3];
}

// ---------------- pass 2b: scan the 49 chunk sums of both arrays (2 waves) ----------------
__global__ void scan_sums_kernel(int* __restrict__ BSD, int* __restrict__ BSS) {
    const int t = threadIdx.x;
    const int lane = t & 63;
    int* bs = (t < 64) ? BSD : BSS;
    int v = (lane < SB) ? bs[lane] : 0;
    int incl = v;
#pragma unroll
    for (int off = 1; off < 64; off <<= 1) {
        int y = __shfl_up(incl, off);
        if (lane >= off) incl += y;
    }
    if (lane < SB) bs[lane] = incl - v;
}

// ---------------- pass 3: deterministic scatter into dst-binned ints + src-binned bytes ----------------
__global__ __launch_bounds__(256) void scatter_kernel(const int* __restrict__ src,
                                                      const int* __restrict__ dst,
                                                      const int* __restrict__ CD, const int* __restrict__ CS,
                                                      const int* __restrict__ BSD, const int* __restrict__ BSS,
                                                      int* __restrict__ binnedD,
                                                      unsigned char* __restrict__ srcb,
                                                      int E, int chunk) {
    __shared__ int curD[NT], curS[NT];
    const int t = threadIdx.x, blk = blockIdx.x;
    for (int i = t; i < NT; i += 256) {
        int idx = i * NB + blk;
        curD[i] = CD[idx] + BSD[idx >> 12];
        curS[i] = CS[idx] + BSS[idx >> 12];
    }
    __syncthreads();
    const int lo = blk * chunk;
    int hi = lo + chunk; if (hi > E) hi = E;
    for (int i = lo + t; i < hi; i += 256) {
        int s = src[i], d = dst[i];
        int p = atomicAdd(&curD[d >> 7], 1);
        binnedD[p] = (s << 7) | (d & 127);
        int ps = atomicAdd(&curS[s >> 7], 1);
        srcb[ps] = (unsigned char)(s & 127);
    }
}

// ---------------- pass 4: per-tile CSR-ify (dst) + deg_out histogram (src) ----------------
__global__ __launch_bounds__(256) void tile_kernel(const int* __restrict__ CD, const int* __restrict__ CS,
                                                   const int* __restrict__ BSD, const int* __restrict__ BSS,
                                                   const int* __restrict__ binnedD,
                                                   const unsigned char* __restrict__ srcb,
                                                   int* __restrict__ csr,
                                                   int* __restrict__ offs, int* __restrict__ cnt,
                                                   int* __restrict__ deg_out, int E) {
    __shared__ int h[128], cur[128];
    __shared__ int w0tot;
    const int bin = blockIdx.x, t = threadIdx.x, lane = t & 63;
    const int i0 = bin * NB;

    // ---- dst phase: histogram 128 nodes, scan, write offs/cnt, place CSR ----
    if (t < 128) h[t] = 0;
    __syncthreads();
    const int base = CD[i0] + BSD[i0 >> 12];
    const int next = (bin + 1 < NT) ? (CD[i0 + NB] + BSD[(i0 + NB) >> 12]) : E;
    const int m = next - base;
    for (int k = t; k < m; k += 256) atomicAdd(&h[binnedD[base + k] & 127], 1);
    __syncthreads();
    int v = (t < 128) ? h[t] : 0;
    int incl = v;
#pragma unroll
    for (int off = 1; off < 64; off <<= 1) {
        int y = __shfl_up(incl, off);
        if (lane >= off) incl += y;
    }
    if (t == 63) w0tot = incl;
    __syncthreads();
    int excl = incl - v + ((t >= 64 && t < 128) ? w0tot : 0);
    if (t < 128) {
        cur[t] = excl;
        int node = bin * 128 + t;
        if (node < N_NODES) { offs[node] = base + excl; cnt[node] = v; }
    }
    __syncthreads();
    for (int k = t; k < m; k += 256) {
        int rec = binnedD[base + k];
        int p = atomicAdd(&cur[rec & 127], 1);
        csr[base + p] = rec >> 7;
    }

    // ---- src phase: histogram the byte stream -> deg_out ----
    __syncthreads();
    if (t < 128) h[t] = 0;
    __syncthreads();
    const int sb = CS[i0] + BSS[i0 >> 12];
    const int sn = (bin + 1 < NT) ? (CS[i0 + NB] + BSS[(i0 + NB) >> 12]) : E;
    const int sm = sn - sb;
    for (int k = t; k < sm; k += 256) atomicAdd(&h[srcb[sb + k]], 1);
    __syncthreads();
    if (t < 128) {
        int node = bin * 128 + t;
        if (node < N_NODES) deg_out[node] = h[t];
    }
}

// ---------------- x = (h * rsqrt(deg_out)[:,None]) @ W   (fp16 output) ----------------
__global__ __launch_bounds__(256) void gemm_kernel(const float* __restrict__ h,
                                                   const float* __restrict__ W,
                                                   const int* __restrict__ deg_out,
                                                   __half* __restrict__ xh) {
    __shared__ float hs[GEMM_ROWS * IN_DIM];
    const int row0 = blockIdx.x * GEMM_ROWS;
    const int t = threadIdx.x;

    const float4* hsrc = (const float4*)(h + (size_t)row0 * IN_DIM);
    float4* hdst = (float4*)hs;
#pragma unroll
    for (int it = 0; it < (GEMM_ROWS * IN_DIM / 4) / 256; ++it) {
        int f = t + it * 256;
        int row = f >> 6;               // f*4 / 256
        int d = deg_out[row0 + row];
        float nrm = rsqrtf((float)(d < 1 ? 1 : d));
        float4 v = hsrc[f];
        v.x *= nrm; v.y *= nrm; v.z *= nrm; v.w *= nrm;
        hdst[f] = v;
    }
    __syncthreads();

    const int j = t & 31;               // column pair (2j, 2j+1)
    const int rg = t >> 5;              // 8 groups x 4 rows
    const float2* W2 = (const float2*)W;
    float acc0[4] = {0.f, 0.f, 0.f, 0.f};
    float acc1[4] = {0.f, 0.f, 0.f, 0.f};

    for (int k = 0; k < IN_DIM; k += 4) {
        float2 w0 = W2[(k + 0) * 32 + j];
        float2 w1 = W2[(k + 1) * 32 + j];
        float2 w2 = W2[(k + 2) * 32 + j];
        float2 w3 = W2[(k + 3) * 32 + j];
#pragma unroll
        for (int r = 0; r < 4; ++r) {
            const float4 hv = *(const float4*)&hs[(rg * 4 + r) * IN_DIM + k];
            acc0[r] = fmaf(hv.x, w0.x, acc0[r]);  acc1[r] = fmaf(hv.x, w0.y, acc1[r]);
            acc0[r] = fmaf(hv.y, w1.x, acc0[r]);  acc1[r] = fmaf(hv.y, w1.y, acc1[r]);
            acc0[r] = fmaf(hv.z, w2.x, acc0[r]);  acc1[r] = fmaf(hv.z, w2.y, acc1[r]);
            acc0[r] = fmaf(hv.w, w3.x, acc0[r]);  acc1[r] = fmaf(hv.w, w3.y, acc1[r]);
        }
    }

    __half2* x2 = (__half2*)xh;
#pragma unroll
    for (int r = 0; r < 4; ++r) {
        int row = row0 + rg * 4 + r;
        x2[(size_t)row * 32 + j] = __float22half2_rn(make_float2(acc0[r], acc1[r]));
    }
}

// ---------------- aggregate: one wave per node, 32 edges staged, 8 loads in flight ----------------
__global__ __launch_bounds__(256) void aggregate_kernel(const int* __restrict__ offs,
                                                        const int* __restrict__ cnt,
                                                        const int* __restrict__ csr,
                                                        const __half* __restrict__ xh,
                                                        const float* __restrict__ b,
                                                        float* __restrict__ out) {
    const int t = threadIdx.x;
    const int lane = t & 63;
    const int wid = t >> 6;
    const int node = blockIdx.x * 4 + wid;          // 25000*4 == N_NODES exactly
    const int g = lane >> 4;
    const int c = lane & 15;

    const int start = offs[node];
    const int n = cnt[node];

    float4 acc = make_float4(0.f, 0.f, 0.f, 0.f);
    for (int base = 0; base < n; base += 64) {
        int k = base + lane;
        int sidx = (k < n) ? csr[start + k] : 0;
        int m = n - base; if (m > 64) m = 64;
        for (int rb = 0; rb < m; rb += 32) {
            uint2 raw[8]; float wq[8];
#pragma unroll
            for (int q = 0; q < 8; ++q) {
                int e = rb + 4 * q + g;              // <= 63 always
                int s = __shfl(sidx, e);
                bool val = e < m;
                s = val ? s : 0;
                wq[q] = val ? 1.f : 0.f;
                raw[q] = *(const uint2*)(xh + (size_t)s * OUT_DIM + 4 * c);
            }
#pragma unroll
            for (int q = 0; q < 8; ++q) {
                float2 f01 = __half22float2(*(__half2*)&raw[q].x);
                float2 f23 = __half22float2(*(__half2*)&raw[q].y);
                acc.x = fmaf(wq[q], f01.x, acc.x);
                acc.y = fmaf(wq[q], f01.y, acc.y);
                acc.z = fmaf(wq[q], f23.x, acc.z);
                acc.w = fmaf(wq[q], f23.y, acc.w);
            }
        }
    }

    acc.x += __shfl_xor(acc.x, 16);  acc.x += __shfl_xor(acc.x, 32);
    acc.y += __shfl_xor(acc.y, 16);  acc.y += __shfl_xor(acc.y, 32);
    acc.z += __shfl_xor(acc.z, 16);  acc.z += __shfl_xor(acc.z, 32);
    acc.w += __shfl_xor(acc.w, 16);  acc.w += __shfl_xor(acc.w, 32);

    if (g == 0) {
        float nrm = rsqrtf((float)(n < 1 ? 1 : n));
        float4 bv = ((const float4*)b)[c];
        float4 r;
        r.x = fmaf(acc.x, nrm, bv.x); r.x = r.x > 0.f ? r.x : 0.f;
        r.y = fmaf(acc.y, nrm, bv.y); r.y = r.y > 0.f ? r.y : 0.f;
        r.z = fmaf(acc.z, nrm, bv.z); r.z = r.z > 0.f ? r.z : 0.f;
        r.w = fmaf(acc.w, nrm, bv.w); r.w = r.w > 0.f ? r.w : 0.f;
        ((float4*)out)[(size_t)node * 16 + c] = r;
    }
}

extern "C" void kernel_launch(void* const* d_in, const int* in_sizes, int n_in,
                              void* d_out, int out_size, void* d_ws, size_t ws_size,
                              hipStream_t stream) {
    const float* h   = (const float*)d_in[0];
    const int*   src = (const int*)d_in[1];
    const int*   dst = (const int*)d_in[2];
    const float* W   = (const float*)d_in[3];
    const float* b   = (const float*)d_in[4];
    float* out = (float*)d_out;
    const int E = in_sizes[1];
    const int chunk = (E + NB - 1) / NB;

    // workspace layout (16B aligned), total ~30 MB; everything is written before read
    char* ws = (char*)d_ws;
    int*           CD      = (int*)(ws);                    // NT*NB ints (800,768 B)
    int*           CS      = (int*)(ws + 800768);           // NT*NB ints
    int*           BSD     = (int*)(ws + 1601536);          // SB ints (padded 256 B)
    int*           BSS     = (int*)(ws + 1601792);          // SB ints
    int*           binnedD = (int*)(ws + 1602048);          // E ints  (6.4 MB)
    unsigned char* srcb    = (unsigned char*)(ws + 8002048);// E bytes (1.6 MB)
    int*           csr     = (int*)(ws + 9602048);          // E ints  (6.4 MB)
    int*           offs    = (int*)(ws + 16002048);         // N ints
    int*           cntA    = (int*)(ws + 16402048);         // N ints
    int*           deg_out = (int*)(ws + 16802048);         // N ints
    __half*        xh      = (__half*)(ws + 17202048);      // N*64 halfs (12.8 MB)

    count_kernel<<<NB, 256, 0, stream>>>(src, dst, CD, CS, E, chunk);
    scan_blocks_kernel<<<2 * SB, 256, 0, stream>>>(CD, CS, BSD, BSS);
    scan_sums_kernel<<<1, 128, 0, stream>>>(BSD, BSS);
    scatter_kernel<<<NB, 256, 0, stream>>>(src, dst, CD, CS, BSD, BSS, binnedD, srcb, E, chunk);
    tile_kernel<<<NT, 256, 0, stream>>>(CD, CS, BSD, BSS, binnedD, srcb, csr, offs, cntA, deg_out, E);
    gemm_kernel<<<N_NODES / GEMM_ROWS, 256, 0, stream>>>(h, W, deg_out, xh);
    aggregate_kernel<<<N_NODES / 4, 256, 0, stream>>>(offs, cntA, csr, xh, b, out);
}

// Round 6
// 302.799 us; speedup vs baseline: 3.4807x; 1.2464x over previous
//
#include <hip/hip_runtime.h>
#include <hip/hip_fp16.h>

#define N_NODES 100000
#define IN_DIM 256
#define OUT_DIM 64
#define NT 782                 // dst/src tiles of 128 nodes
#define NB 256                 // binning blocks
#define SCHUNK 4096            // scan chunk: 256 threads * 16
#define SB ((NT * NB + SCHUNK - 1) / SCHUNK)   // 49 scan blocks per array
#define SCAN_M (NT * NB)       // 200192

typedef _Float16 half8 __attribute__((ext_vector_type(8)));
typedef float f32x4 __attribute__((ext_vector_type(4)));

// ---------------- pass 1: per-block LDS histograms of dst>>7 and src>>7 ----------------
__global__ __launch_bounds__(256) void count_kernel(const int* __restrict__ src,
                                                    const int* __restrict__ dst,
                                                    int* __restrict__ CD, int* __restrict__ CS,
                                                    int E, int chunk) {
    __shared__ int hd[NT], hs[NT];
    const int t = threadIdx.x, blk = blockIdx.x;
    for (int i = t; i < NT; i += 256) { hd[i] = 0; hs[i] = 0; }
    __syncthreads();
    const int lo = blk * chunk;
    int hi = lo + chunk; if (hi > E) hi = E;
    for (int i = lo + t; i < hi; i += 256) {
        atomicAdd(&hd[dst[i] >> 7], 1);
        atomicAdd(&hs[src[i] >> 7], 1);
    }
    __syncthreads();
    for (int i = t; i < NT; i += 256) {
        CD[i * NB + blk] = hd[i];
        CS[i * NB + blk] = hs[i];
    }
}

// ---------------- pass 2a: chunk-local exclusive scan of CD and CS (in place) ----------------
__global__ __launch_bounds__(256) void scan_blocks_kernel(int* __restrict__ CD, int* __restrict__ CS,
                                                          int* __restrict__ BSD, int* __restrict__ BSS) {
    int cid = blockIdx.x;
    int* arr; int* bs;
    if (cid < SB) { arr = CD; bs = BSD; } else { arr = CS; bs = BSS; cid -= SB; }
    const int t = threadIdx.x;
    const int base = cid * SCHUNK + t * 16;
    int pre[16];
    int s = 0;
#pragma unroll
    for (int r = 0; r < 16; ++r) {
        int v = (base + r < SCAN_M) ? arr[base + r] : 0;
        pre[r] = s; s += v;
    }
    const int lane = t & 63;
    int incl = s;
#pragma unroll
    for (int off = 1; off < 64; off <<= 1) {
        int y = __shfl_up(incl, off);
        if (lane >= off) incl += y;
    }
    int wave_excl = incl - s;
    __shared__ int wtot[4];
    if (lane == 63) wtot[t >> 6] = incl;
    __syncthreads();
    int woff = 0;
    for (int w = 0; w < (t >> 6); ++w) woff += wtot[w];
    int bexcl = woff + wave_excl;
#pragma unroll
    for (int r = 0; r < 16; ++r)
        if (base + r < SCAN_M) arr[base + r] = bexcl + pre[r];
    if (t == 0) bs[cid] = wtot[0] + wtot[1] + wtot[2] + wtot[3];
}

// ---------------- pass 2b: scan the 49 chunk sums of both arrays (2 waves) ----------------
__global__ void scan_sums_kernel(int* __restrict__ BSD, int* __restrict__ BSS) {
    const int t = threadIdx.x;
    const int lane = t & 63;
    int* bs = (t < 64) ? BSD : BSS;
    int v = (lane < SB) ? bs[lane] : 0;
    int incl = v;
#pragma unroll
    for (int off = 1; off < 64; off <<= 1) {
        int y = __shfl_up(incl, off);
        if (lane >= off) incl += y;
    }
    if (lane < SB) bs[lane] = incl - v;
}

// ---------------- pass 3: deterministic scatter into dst-binned ints + src-binned bytes ----------------
__global__ __launch_bounds__(256) void scatter_kernel(const int* __restrict__ src,
                                                      const int* __restrict__ dst,
                                                      const int* __restrict__ CD, const int* __restrict__ CS,
                                                      const int* __restrict__ BSD, const int* __restrict__ BSS,
                                                      int* __restrict__ binnedD,
                                                      unsigned char* __restrict__ srcb,
                                                      int E, int chunk) {
    __shared__ int curD[NT], curS[NT];
    const int t = threadIdx.x, blk = blockIdx.x;
    for (int i = t; i < NT; i += 256) {
        int idx = i * NB + blk;
        curD[i] = CD[idx] + BSD[idx >> 12];
        curS[i] = CS[idx] + BSS[idx >> 12];
    }
    __syncthreads();
    const int lo = blk * chunk;
    int hi = lo + chunk; if (hi > E) hi = E;
    for (int i = lo + t; i < hi; i += 256) {
        int s = src[i], d = dst[i];
        int p = atomicAdd(&curD[d >> 7], 1);
        binnedD[p] = (s << 7) | (d & 127);
        int ps = atomicAdd(&curS[s >> 7], 1);
        srcb[ps] = (unsigned char)(s & 127);
    }
}

// ---------------- pass 4: per-tile CSR-ify (dst) + deg_out histogram (src) ----------------
__global__ __launch_bounds__(256) void tile_kernel(const int* __restrict__ CD, const int* __restrict__ CS,
                                                   const int* __restrict__ BSD, const int* __restrict__ BSS,
                                                   const int* __restrict__ binnedD,
                                                   const unsigned char* __restrict__ srcb,
                                                   int* __restrict__ csr,
                                                   int* __restrict__ offs, int* __restrict__ cnt,
                                                   int* __restrict__ deg_out, int E) {
    __shared__ int h[128], cur[128];
    __shared__ int w0tot;
    const int bin = blockIdx.x, t = threadIdx.x, lane = t & 63;
    const int i0 = bin * NB;

    // ---- dst phase: histogram 128 nodes, scan, write offs/cnt, place CSR ----
    if (t < 128) h[t] = 0;
    __syncthreads();
    const int base = CD[i0] + BSD[i0 >> 12];
    const int next = (bin + 1 < NT) ? (CD[i0 + NB] + BSD[(i0 + NB) >> 12]) : E;
    const int m = next - base;
    for (int k = t; k < m; k += 256) atomicAdd(&h[binnedD[base + k] & 127], 1);
    __syncthreads();
    int v = (t < 128) ? h[t] : 0;
    int incl = v;
#pragma unroll
    for (int off = 1; off < 64; off <<= 1) {
        int y = __shfl_up(incl, off);
        if (lane >= off) incl += y;
    }
    if (t == 63) w0tot = incl;
    __syncthreads();
    int excl = incl - v + ((t >= 64 && t < 128) ? w0tot : 0);
    if (t < 128) {
        cur[t] = excl;
        int node = bin * 128 + t;
        if (node < N_NODES) { offs[node] = base + excl; cnt[node] = v; }
    }
    __syncthreads();
    for (int k = t; k < m; k += 256) {
        int rec = binnedD[base + k];
        int p = atomicAdd(&cur[rec & 127], 1);
        csr[base + p] = rec >> 7;
    }

    // ---- src phase: histogram the byte stream -> deg_out ----
    __syncthreads();
    if (t < 128) h[t] = 0;
    __syncthreads();
    const int sb = CS[i0] + BSS[i0 >> 12];
    const int sn = (bin + 1 < NT) ? (CS[i0 + NB] + BSS[(i0 + NB) >> 12]) : E;
    const int sm = sn - sb;
    for (int k = t; k < sm; k += 256) atomicAdd(&h[srcb[sb + k]], 1);
    __syncthreads();
    if (t < 128) {
        int node = bin * 128 + t;
        if (node < N_NODES) deg_out[node] = h[t];
    }
}

// ---------------- MFMA GEMM: x = fp16(h * rsqrt(deg_out)) @ fp16(W), fp32 accum ----------------
// block = 64 rows x 64 cols, K=256 in two 128-halves. LDS: sA[64][136] + sB[64][136] fp16
// (pad 8 -> rows 16B-aligned, ds_read_b128 fragment reads only 2-way bank-aliased = free).
// wave w: m0=(w&1)*32, n0=(w>>1)*32; 4 mfma_f32_16x16x32_f16 per K-step.
#define A_LD 136
__global__ __launch_bounds__(256) void gemm_kernel(const float* __restrict__ hmat,
                                                   const float* __restrict__ W,
                                                   const int* __restrict__ deg_out,
                                                   __half* __restrict__ xh) {
    __shared__ _Float16 sA[64 * A_LD];
    __shared__ _Float16 sB[64 * A_LD];
    const int t = threadIdx.x;
    const int lane = t & 63;
    const int w = t >> 6;
    const int row0 = blockIdx.x * 64;
    const int m0 = (w & 1) * 32;
    const int n0 = (w >> 1) * 32;

    f32x4 acc00 = {0.f, 0.f, 0.f, 0.f}, acc01 = {0.f, 0.f, 0.f, 0.f};
    f32x4 acc10 = {0.f, 0.f, 0.f, 0.f}, acc11 = {0.f, 0.f, 0.f, 0.f};

    for (int khalf = 0; khalf < 2; ++khalf) {
        const int k0 = khalf * 128;
        __syncthreads();   // protect LDS from previous half's reads
        // stage A: 64 rows x 128 cols -> 2048 float4, 8 per thread, coalesced
#pragma unroll
        for (int it = 0; it < 8; ++it) {
            int f = t + it * 256;
            int row = f >> 5;            // 32 float4 per row
            int c4 = f & 31;
            int grow = row0 + row; if (grow >= N_NODES) grow = N_NODES - 1;
            int d = deg_out[grow];
            float nrm = rsqrtf((float)(d < 1 ? 1 : d));
            float4 v = *(const float4*)(hmat + (size_t)grow * IN_DIM + k0 + c4 * 4);
            _Float16 p[4];
            p[0] = (_Float16)(v.x * nrm); p[1] = (_Float16)(v.y * nrm);
            p[2] = (_Float16)(v.z * nrm); p[3] = (_Float16)(v.w * nrm);
            *(uint2*)&sA[row * A_LD + c4 * 4] = *(uint2*)p;
        }
        // stage B transposed: sB[n][k] = W[k0+k][n]; coalesced global reads
        {
            int n = t & 63;
#pragma unroll
            for (int kk = (t >> 6); kk < 128; kk += 4)
                sB[n * A_LD + kk] = (_Float16)W[(size_t)(k0 + kk) * OUT_DIM + n];
        }
        __syncthreads();
        // 4 K-steps of 32
#pragma unroll
        for (int kb = 0; kb < 4; ++kb) {
            int koff = kb * 32 + (lane >> 4) * 8;
            half8 a0 = *(const half8*)&sA[(m0 + (lane & 15)) * A_LD + koff];
            half8 a1 = *(const half8*)&sA[(m0 + 16 + (lane & 15)) * A_LD + koff];
            half8 b0 = *(const half8*)&sB[(n0 + (lane & 15)) * A_LD + koff];
            half8 b1 = *(const half8*)&sB[(n0 + 16 + (lane & 15)) * A_LD + koff];
            acc00 = __builtin_amdgcn_mfma_f32_16x16x32_f16(a0, b0, acc00, 0, 0, 0);
            acc01 = __builtin_amdgcn_mfma_f32_16x16x32_f16(a0, b1, acc01, 0, 0, 0);
            acc10 = __builtin_amdgcn_mfma_f32_16x16x32_f16(a1, b0, acc10, 0, 0, 0);
            acc11 = __builtin_amdgcn_mfma_f32_16x16x32_f16(a1, b1, acc11, 0, 0, 0);
        }
    }

    // epilogue: C/D layout col=lane&15, row=(lane>>4)*4+reg (m89-verified)
    const int col16 = lane & 15;
    const int rq = (lane >> 4) * 4;
#pragma unroll
    for (int mi = 0; mi < 2; ++mi) {
#pragma unroll
        for (int ni = 0; ni < 2; ++ni) {
            const f32x4 a = (mi == 0) ? (ni == 0 ? acc00 : acc01)
                                      : (ni == 0 ? acc10 : acc11);
            int col = n0 + ni * 16 + col16;
#pragma unroll
            for (int r = 0; r < 4; ++r) {
                int row = row0 + m0 + mi * 16 + rq + r;
                if (row < N_NODES)
                    xh[(size_t)row * OUT_DIM + col] = __float2half(a[r]);
            }
        }
    }
}

// ---------------- aggregate: one wave per node, 32 edges staged, 8 loads in flight ----------------
__global__ __launch_bounds__(256) void aggregate_kernel(const int* __restrict__ offs,
                                                        const int* __restrict__ cnt,
                                                        const int* __restrict__ csr,
                                                        const __half* __restrict__ xh,
                                                        const float* __restrict__ b,
                                                        float* __restrict__ out) {
    const int t = threadIdx.x;
    const int lane = t & 63;
    const int wid = t >> 6;
    const int node = blockIdx.x * 4 + wid;          // 25000*4 == N_NODES exactly
    const int g = lane >> 4;
    const int c = lane & 15;

    const int start = offs[node];
    const int n = cnt[node];

    float4 acc = make_float4(0.f, 0.f, 0.f, 0.f);
    for (int base = 0; base < n; base += 64) {
        int k = base + lane;
        int sidx = (k < n) ? csr[start + k] : 0;
        int m = n - base; if (m > 64) m = 64;
        for (int rb = 0; rb < m; rb += 32) {
            uint2 raw[8]; float wq[8];
#pragma unroll
            for (int q = 0; q < 8; ++q) {
                int e = rb + 4 * q + g;              // <= 63 always
                int s = __shfl(sidx, e);
                bool val = e < m;
                s = val ? s : 0;
                wq[q] = val ? 1.f : 0.f;
                raw[q] = *(const uint2*)(xh + (size_t)s * OUT_DIM + 4 * c);
            }
#pragma unroll
            for (int q = 0; q < 8; ++q) {
                float2 f01 = __half22float2(*(__half2*)&raw[q].x);
                float2 f23 = __half22float2(*(__half2*)&raw[q].y);
                acc.x = fmaf(wq[q], f01.x, acc.x);
                acc.y = fmaf(wq[q], f01.y, acc.y);
                acc.z = fmaf(wq[q], f23.x, acc.z);
                acc.w = fmaf(wq[q], f23.y, acc.w);
            }
        }
    }

    acc.x += __shfl_xor(acc.x, 16);  acc.x += __shfl_xor(acc.x, 32);
    acc.y += __shfl_xor(acc.y, 16);  acc.y += __shfl_xor(acc.y, 32);
    acc.z += __shfl_xor(acc.z, 16);  acc.z += __shfl_xor(acc.z, 32);
    acc.w += __shfl_xor(acc.w, 16);  acc.w += __shfl_xor(acc.w, 32);

    if (g == 0) {
        float nrm = rsqrtf((float)(n < 1 ? 1 : n));
        float4 bv = ((const float4*)b)[c];
        float4 r;
        r.x = fmaf(acc.x, nrm, bv.x); r.x = r.x > 0.f ? r.x : 0.f;
        r.y = fmaf(acc.y, nrm, bv.y); r.y = r.y > 0.f ? r.y : 0.f;
        r.z = fmaf(acc.z, nrm, bv.z); r.z = r.z > 0.f ? r.z : 0.f;
        r.w = fmaf(acc.w, nrm, bv.w); r.w = r.w > 0.f ? r.w : 0.f;
        ((float4*)out)[(size_t)node * 16 + c] = r;
    }
}

extern "C" void kernel_launch(void* const* d_in, const int* in_sizes, int n_in,
                              void* d_out, int out_size, void* d_ws, size_t ws_size,
                              hipStream_t stream) {
    const float* h   = (const float*)d_in[0];
    const int*   src = (const int*)d_in[1];
    const int*   dst = (const int*)d_in[2];
    const float* W   = (const float*)d_in[3];
    const float* b   = (const float*)d_in[4];
    float* out = (float*)d_out;
    const int E = in_sizes[1];
    const int chunk = (E + NB - 1) / NB;

    // workspace layout (16B aligned), total ~30 MB; everything is written before read
    char* ws = (char*)d_ws;
    int*           CD      = (int*)(ws);                    // NT*NB ints (800,768 B)
    int*           CS      = (int*)(ws + 800768);           // NT*NB ints
    int*           BSD     = (int*)(ws + 1601536);          // SB ints (padded 256 B)
    int*           BSS     = (int*)(ws + 1601792);          // SB ints
    int*           binnedD = (int*)(ws + 1602048);          // E ints  (6.4 MB)
    unsigned char* srcb    = (unsigned char*)(ws + 8002048);// E bytes (1.6 MB)
    int*           csr     = (int*)(ws + 9602048);          // E ints  (6.4 MB)
    int*           offs    = (int*)(ws + 16002048);         // N ints
    int*           cntA    = (int*)(ws + 16402048);         // N ints
    int*           deg_out = (int*)(ws + 16802048);         // N ints
    __half*        xh      = (__half*)(ws + 17202048);      // N*64 halfs (12.8 MB)

    count_kernel<<<NB, 256, 0, stream>>>(src, dst, CD, CS, E, chunk);
    scan_blocks_kernel<<<2 * SB, 256, 0, stream>>>(CD, CS, BSD, BSS);
    scan_sums_kernel<<<1, 128, 0, stream>>>(BSD, BSS);
    scatter_kernel<<<NB, 256, 0, stream>>>(src, dst, CD, CS, BSD, BSS, binnedD, srcb, E, chunk);
    tile_kernel<<<NT, 256, 0, stream>>>(CD, CS, BSD, BSS, binnedD, srcb, csr, offs, cntA, deg_out, E);
    gemm_kernel<<<(N_NODES + 63) / 64, 256, 0, stream>>>(h, W, deg_out, xh);
    aggregate_kernel<<<N_NODES / 4, 256, 0, stream>>>(offs, cntA, csr, xh, b, out);
}

// Round 7
// 295.306 us; speedup vs baseline: 3.5690x; 1.0254x over previous
//
#include <hip/hip_runtime.h>
#include <hip/hip_fp16.h>

#define N_NODES 100000
#define IN_DIM 256
#define OUT_DIM 64
#define NT 782                 // dst/src tiles of 128 nodes
#define NB 256                 // binning blocks
#define SCHUNK 4096            // scan chunk: 256 threads * 16
#define SB ((NT * NB + SCHUNK - 1) / SCHUNK)   // 49 scan blocks per array
#define SCAN_M (NT * NB)       // 200192

typedef _Float16 half8 __attribute__((ext_vector_type(8)));
typedef float f32x4 __attribute__((ext_vector_type(4)));

// ---------------- pass 1: per-block LDS histograms of dst>>7 and src>>7 ----------------
__global__ __launch_bounds__(256) void count_kernel(const int* __restrict__ src,
                                                    const int* __restrict__ dst,
                                                    int* __restrict__ CD, int* __restrict__ CS,
                                                    int E, int chunk) {
    __shared__ int hd[NT], hs[NT];
    const int t = threadIdx.x, blk = blockIdx.x;
    for (int i = t; i < NT; i += 256) { hd[i] = 0; hs[i] = 0; }
    __syncthreads();
    const int lo = blk * chunk;
    int hi = lo + chunk; if (hi > E) hi = E;
    for (int i = lo + t; i < hi; i += 256) {
        atomicAdd(&hd[dst[i] >> 7], 1);
        atomicAdd(&hs[src[i] >> 7], 1);
    }
    __syncthreads();
    for (int i = t; i < NT; i += 256) {
        CD[i * NB + blk] = hd[i];
        CS[i * NB + blk] = hs[i];
    }
}

// ---------------- pass 2a: chunk-local exclusive scan of CD and CS (in place) ----------------
__global__ __launch_bounds__(256) void scan_blocks_kernel(int* __restrict__ CD, int* __restrict__ CS,
                                                          int* __restrict__ BSD, int* __restrict__ BSS) {
    int cid = blockIdx.x;
    int* arr; int* bs;
    if (cid < SB) { arr = CD; bs = BSD; } else { arr = CS; bs = BSS; cid -= SB; }
    const int t = threadIdx.x;
    const int base = cid * SCHUNK + t * 16;
    int pre[16];
    int s = 0;
#pragma unroll
    for (int r = 0; r < 16; ++r) {
        int v = (base + r < SCAN_M) ? arr[base + r] : 0;
        pre[r] = s; s += v;
    }
    const int lane = t & 63;
    int incl = s;
#pragma unroll
    for (int off = 1; off < 64; off <<= 1) {
        int y = __shfl_up(incl, off);
        if (lane >= off) incl += y;
    }
    int wave_excl = incl - s;
    __shared__ int wtot[4];
    if (lane == 63) wtot[t >> 6] = incl;
    __syncthreads();
    int woff = 0;
    for (int w = 0; w < (t >> 6); ++w) woff += wtot[w];
    int bexcl = woff + wave_excl;
#pragma unroll
    for (int r = 0; r < 16; ++r)
        if (base + r < SCAN_M) arr[base + r] = bexcl + pre[r];
    if (t == 0) bs[cid] = wtot[0] + wtot[1] + wtot[2] + wtot[3];
}

// ---------------- pass 2b: scan the 49 chunk sums of both arrays (2 waves) ----------------
__global__ void scan_sums_kernel(int* __restrict__ BSD, int* __restrict__ BSS) {
    const int t = threadIdx.x;
    const int lane = t & 63;
    int* bs = (t < 64) ? BSD : BSS;
    int v = (lane < SB) ? bs[lane] : 0;
    int incl = v;
#pragma unroll
    for (int off = 1; off < 64; off <<= 1) {
        int y = __shfl_up(incl, off);
        if (lane >= off) incl += y;
    }
    if (lane < SB) bs[lane] = incl - v;
}

// ---------------- pass 3: deterministic scatter into dst-binned ints + src-binned bytes ----------------
__global__ __launch_bounds__(256) void scatter_kernel(const int* __restrict__ src,
                                                      const int* __restrict__ dst,
                                                      const int* __restrict__ CD, const int* __restrict__ CS,
                                                      const int* __restrict__ BSD, const int* __restrict__ BSS,
                                                      int* __restrict__ binnedD,
                                                      unsigned char* __restrict__ srcb,
                                                      int E, int chunk) {
    __shared__ int curD[NT], curS[NT];
    const int t = threadIdx.x, blk = blockIdx.x;
    for (int i = t; i < NT; i += 256) {
        int idx = i * NB + blk;
        curD[i] = CD[idx] + BSD[idx >> 12];
        curS[i] = CS[idx] + BSS[idx >> 12];
    }
    __syncthreads();
    const int lo = blk * chunk;
    int hi = lo + chunk; if (hi > E) hi = E;
    for (int i = lo + t; i < hi; i += 256) {
        int s = src[i], d = dst[i];
        int p = atomicAdd(&curD[d >> 7], 1);
        binnedD[p] = (s << 7) | (d & 127);
        int ps = atomicAdd(&curS[s >> 7], 1);
        srcb[ps] = (unsigned char)(s & 127);
    }
}

// ---------------- pass 4: per-tile CSR-ify (dst) + deg_out histogram (src) ----------------
__global__ __launch_bounds__(256) void tile_kernel(const int* __restrict__ CD, const int* __restrict__ CS,
                                                   const int* __restrict__ BSD, const int* __restrict__ BSS,
                                                   const int* __restrict__ binnedD,
                                                   const unsigned char* __restrict__ srcb,
                                                   int* __restrict__ csr,
                                                   int* __restrict__ offs, int* __restrict__ cnt,
                                                   int* __restrict__ deg_out, int E) {
    __shared__ int h[128], cur[128];
    __shared__ int w0tot;
    const int bin = blockIdx.x, t = threadIdx.x, lane = t & 63;
    const int i0 = bin * NB;

    // ---- dst phase: histogram 128 nodes, scan, write offs/cnt, place CSR ----
    if (t < 128) h[t] = 0;
    __syncthreads();
    const int base = CD[i0] + BSD[i0 >> 12];
    const int next = (bin + 1 < NT) ? (CD[i0 + NB] + BSD[(i0 + NB) >> 12]) : E;
    const int m = next - base;
    for (int k = t; k < m; k += 256) atomicAdd(&h[binnedD[base + k] & 127], 1);
    __syncthreads();
    int v = (t < 128) ? h[t] : 0;
    int incl = v;
#pragma unroll
    for (int off = 1; off < 64; off <<= 1) {
        int y = __shfl_up(incl, off);
        if (lane >= off) incl += y;
    }
    if (t == 63) w0tot = incl;
    __syncthreads();
    int excl = incl - v + ((t >= 64 && t < 128) ? w0tot : 0);
    if (t < 128) {
        cur[t] = excl;
        int node = bin * 128 + t;
        if (node < N_NODES) { offs[node] = base + excl; cnt[node] = v; }
    }
    __syncthreads();
    for (int k = t; k < m; k += 256) {
        int rec = binnedD[base + k];
        int p = atomicAdd(&cur[rec & 127], 1);
        csr[base + p] = rec >> 7;
    }

    // ---- src phase: histogram the byte stream -> deg_out ----
    __syncthreads();
    if (t < 128) h[t] = 0;
    __syncthreads();
    const int sb = CS[i0] + BSS[i0 >> 12];
    const int sn = (bin + 1 < NT) ? (CS[i0 + NB] + BSS[(i0 + NB) >> 12]) : E;
    const int sm = sn - sb;
    for (int k = t; k < sm; k += 256) atomicAdd(&h[srcb[sb + k]], 1);
    __syncthreads();
    if (t < 128) {
        int node = bin * 128 + t;
        if (node < N_NODES) deg_out[node] = h[t];
    }
}

// ---------------- MFMA GEMM: x = fp16(h) @ fp16(W), row-scaled by rsqrt(deg_out) in epilogue ----------------
// block = 64 rows x 64 cols, K=256 in two 128-halves. LDS: sA[64][136] + sB[64][136] fp16
// (pad 8 -> rows 16B-aligned, ds_read_b128 fragment reads only 2-way bank-aliased = free).
// wave w: m0=(w&1)*32, n0=(w>>1)*32; 4 mfma_f32_16x16x32_f16 per K-step.
#define A_LD 136
__global__ __launch_bounds__(256) void gemm_kernel(const float* __restrict__ hmat,
                                                   const float* __restrict__ W,
                                                   const int* __restrict__ deg_out,
                                                   __half* __restrict__ xh) {
    __shared__ _Float16 sA[64 * A_LD];
    __shared__ _Float16 sB[64 * A_LD];
    const int t = threadIdx.x;
    const int lane = t & 63;
    const int w = t >> 6;
    const int row0 = blockIdx.x * 64;
    const int m0 = (w & 1) * 32;
    const int n0 = (w >> 1) * 32;

    f32x4 acc00 = {0.f, 0.f, 0.f, 0.f}, acc01 = {0.f, 0.f, 0.f, 0.f};
    f32x4 acc10 = {0.f, 0.f, 0.f, 0.f}, acc11 = {0.f, 0.f, 0.f, 0.f};

    for (int khalf = 0; khalf < 2; ++khalf) {
        const int k0 = khalf * 128;
        __syncthreads();   // protect LDS from previous half's reads
        // stage A: pure fp32->fp16 convert-copy (norm folded into epilogue)
#pragma unroll
        for (int it = 0; it < 8; ++it) {
            int f = t + it * 256;
            int row = f >> 5;            // 32 float4 per row
            int c4 = f & 31;
            int grow = row0 + row; if (grow >= N_NODES) grow = N_NODES - 1;
            float4 v = *(const float4*)(hmat + (size_t)grow * IN_DIM + k0 + c4 * 4);
            _Float16 p[4];
            p[0] = (_Float16)v.x; p[1] = (_Float16)v.y;
            p[2] = (_Float16)v.z; p[3] = (_Float16)v.w;
            *(uint2*)&sA[row * A_LD + c4 * 4] = *(uint2*)p;
        }
        // stage B transposed: sB[n][k] = W[k0+k][n]; packed uint2 LDS writes
        {
            int n = t & 63;
            int kk0 = (t >> 6) * 32;
#pragma unroll
            for (int kb = 0; kb < 8; ++kb) {
                _Float16 p[4];
#pragma unroll
                for (int u = 0; u < 4; ++u)
                    p[u] = (_Float16)W[(size_t)(k0 + kk0 + kb * 4 + u) * OUT_DIM + n];
                *(uint2*)&sB[n * A_LD + kk0 + kb * 4] = *(uint2*)p;
            }
        }
        __syncthreads();
        // 4 K-steps of 32
#pragma unroll
        for (int kb = 0; kb < 4; ++kb) {
            int koff = kb * 32 + (lane >> 4) * 8;
            half8 a0 = *(const half8*)&sA[(m0 + (lane & 15)) * A_LD + koff];
            half8 a1 = *(const half8*)&sA[(m0 + 16 + (lane & 15)) * A_LD + koff];
            half8 b0 = *(const half8*)&sB[(n0 + (lane & 15)) * A_LD + koff];
            half8 b1 = *(const half8*)&sB[(n0 + 16 + (lane & 15)) * A_LD + koff];
            acc00 = __builtin_amdgcn_mfma_f32_16x16x32_f16(a0, b0, acc00, 0, 0, 0);
            acc01 = __builtin_amdgcn_mfma_f32_16x16x32_f16(a0, b1, acc01, 0, 0, 0);
            acc10 = __builtin_amdgcn_mfma_f32_16x16x32_f16(a1, b0, acc10, 0, 0, 0);
            acc11 = __builtin_amdgcn_mfma_f32_16x16x32_f16(a1, b1, acc11, 0, 0, 0);
        }
    }

    // epilogue: C/D layout col=lane&15, row=(lane>>4)*4+reg (m89-verified); apply row norm here
    const int col16 = lane & 15;
    const int rq = (lane >> 4) * 4;
#pragma unroll
    for (int mi = 0; mi < 2; ++mi) {
        float nrm[4];
#pragma unroll
        for (int r = 0; r < 4; ++r) {
            int row = row0 + m0 + mi * 16 + rq + r;
            int d = (row < N_NODES) ? deg_out[row] : 1;
            nrm[r] = rsqrtf((float)(d < 1 ? 1 : d));
        }
#pragma unroll
        for (int ni = 0; ni < 2; ++ni) {
            const f32x4 a = (mi == 0) ? (ni == 0 ? acc00 : acc01)
                                      : (ni == 0 ? acc10 : acc11);
            int col = n0 + ni * 16 + col16;
#pragma unroll
            for (int r = 0; r < 4; ++r) {
                int row = row0 + m0 + mi * 16 + rq + r;
                if (row < N_NODES)
                    xh[(size_t)row * OUT_DIM + col] = __float2half(a[r] * nrm[r]);
            }
        }
    }
}

// ---------------- aggregate: one wave per node, 8 lanes x 16B per edge row ----------------
// g = lane>>3 (edge group), c = lane&7 (16B col-block): one load instruction covers 8 edges.
// raw[4] keeps 4 KB/wave in flight; dummy edges load row 0 (L1-resident).
__global__ __launch_bounds__(256) void aggregate_kernel(const int* __restrict__ offs,
                                                        const int* __restrict__ cnt,
                                                        const int* __restrict__ csr,
                                                        const __half* __restrict__ xh,
                                                        const float* __restrict__ b,
                                                        float* __restrict__ out) {
    const int t = threadIdx.x;
    const int lane = t & 63;
    const int wid = t >> 6;
    const int node = blockIdx.x * 4 + wid;          // 25000*4 == N_NODES exactly
    const int g = lane >> 3;
    const int c = lane & 7;

    const int start = offs[node];
    const int n = cnt[node];

    float acc[8] = {0.f, 0.f, 0.f, 0.f, 0.f, 0.f, 0.f, 0.f};
    for (int base = 0; base < n; base += 64) {
        int k = base + lane;
        int sidx = (k < n) ? csr[start + k] : 0;
        int m = n - base; if (m > 64) m = 64;
        for (int rb = 0; rb < m; rb += 32) {
            uint4 raw[4]; float wq[4];
#pragma unroll
            for (int q = 0; q < 4; ++q) {
                int e = rb + 8 * q + g;              // <= 63 always
                int s = __shfl(sidx, e);
                bool val = e < m;
                s = val ? s : 0;
                wq[q] = val ? 1.f : 0.f;
                raw[q] = *(const uint4*)(xh + (size_t)s * OUT_DIM + 8 * c);
            }
#pragma unroll
            for (int q = 0; q < 4; ++q) {
                const __half2* hp = (const __half2*)&raw[q];
#pragma unroll
                for (int p = 0; p < 4; ++p) {
                    float2 f = __half22float2(hp[p]);
                    acc[2 * p]     = fmaf(wq[q], f.x, acc[2 * p]);
                    acc[2 * p + 1] = fmaf(wq[q], f.y, acc[2 * p + 1]);
                }
            }
        }
    }

    // reduce over the 8 edge groups (lanes c, c+8, ..., c+56)
#pragma unroll
    for (int off = 8; off < 64; off <<= 1) {
#pragma unroll
        for (int p = 0; p < 8; ++p)
            acc[p] += __shfl_xor(acc[p], off);
    }

    if (g == 0) {   // lanes 0..7 hold the full sums for cols c*8..c*8+7
        float nrm = rsqrtf((float)(n < 1 ? 1 : n));
        float4 bv0 = *(const float4*)&b[c * 8];
        float4 bv1 = *(const float4*)&b[c * 8 + 4];
        float4 r0, r1;
        r0.x = fmaxf(fmaf(acc[0], nrm, bv0.x), 0.f);
        r0.y = fmaxf(fmaf(acc[1], nrm, bv0.y), 0.f);
        r0.z = fmaxf(fmaf(acc[2], nrm, bv0.z), 0.f);
        r0.w = fmaxf(fmaf(acc[3], nrm, bv0.w), 0.f);
        r1.x = fmaxf(fmaf(acc[4], nrm, bv1.x), 0.f);
        r1.y = fmaxf(fmaf(acc[5], nrm, bv1.y), 0.f);
        r1.z = fmaxf(fmaf(acc[6], nrm, bv1.z), 0.f);
        r1.w = fmaxf(fmaf(acc[7], nrm, bv1.w), 0.f);
        float4* orow = (float4*)(out + (size_t)node * OUT_DIM + c * 8);
        orow[0] = r0;
        orow[1] = r1;
    }
}

extern "C" void kernel_launch(void* const* d_in, const int* in_sizes, int n_in,
                              void* d_out, int out_size, void* d_ws, size_t ws_size,
                              hipStream_t stream) {
    const float* h   = (const float*)d_in[0];
    const int*   src = (const int*)d_in[1];
    const int*   dst = (const int*)d_in[2];
    const float* W   = (const float*)d_in[3];
    const float* b   = (const float*)d_in[4];
    float* out = (float*)d_out;
    const int E = in_sizes[1];
    const int chunk = (E + NB - 1) / NB;

    // workspace layout (16B aligned), total ~30 MB; everything is written before read
    char* ws = (char*)d_ws;
    int*           CD      = (int*)(ws);                    // NT*NB ints (800,768 B)
    int*           CS      = (int*)(ws + 800768);           // NT*NB ints
    int*           BSD     = (int*)(ws + 1601536);          // SB ints (padded 256 B)
    int*           BSS     = (int*)(ws + 1601792);          // SB ints
    int*           binnedD = (int*)(ws + 1602048);          // E ints  (6.4 MB)
    unsigned char* srcb    = (unsigned char*)(ws + 8002048);// E bytes (1.6 MB)
    int*           csr     = (int*)(ws + 9602048);          // E ints  (6.4 MB)
    int*           offs    = (int*)(ws + 16002048);         // N ints
    int*           cntA    = (int*)(ws + 16402048);         // N ints
    int*           deg_out = (int*)(ws + 16802048);         // N ints
    __half*        xh      = (__half*)(ws + 17202048);      // N*64 halfs (12.8 MB)

    count_kernel<<<NB, 256, 0, stream>>>(src, dst, CD, CS, E, chunk);
    scan_blocks_kernel<<<2 * SB, 256, 0, stream>>>(CD, CS, BSD, BSS);
    scan_sums_kernel<<<1, 128, 0, stream>>>(BSD, BSS);
    scatter_kernel<<<NB, 256, 0, stream>>>(src, dst, CD, CS, BSD, BSS, binnedD, srcb, E, chunk);
    tile_kernel<<<NT, 256, 0, stream>>>(CD, CS, BSD, BSS, binnedD, srcb, csr, offs, cntA, deg_out, E);
    gemm_kernel<<<(N_NODES + 63) / 64, 256, 0, stream>>>(h, W, deg_out, xh);
    aggregate_kernel<<<N_NODES / 4, 256, 0, stream>>>(offs, cntA, csr, xh, b, out);
}